// Round 1
// baseline (127.061 us; speedup 1.0000x reference)
//
#include <hip/hip_runtime.h>
#include <math.h>

#define B_ROWS 4096
#define T_COLS 4096
#define NTHREADS 1024
#define CHUNK 4                  // elements per thread == one float4: ownership == coalescing
#define NWAVES (NTHREADS / 64)   // 16

// Force a (wave-uniform) float into an SGPR.
__device__ __forceinline__ float rfl(float v) {
    return __int_as_float(__builtin_amdgcn_readfirstlane(__float_as_int(v)));
}

__global__ __launch_bounds__(NTHREADS, 8) void garch_fused(
    const float* __restrict__ x,
    const float* __restrict__ p_omega_log,
    const float* __restrict__ p_alpha_log,
    const float* __restrict__ p_beta_log,
    float* __restrict__ out)
{
    // Only cross-wave handoff state lives in LDS now (256 B).
    __shared__ float wA[NWAVES], wB[NWAVES], rSum[NWAVES], rSsq[NWAVES];

    const int t    = threadIdx.x;
    const int lane = t & 63;
    const int wv   = t >> 6;
    const long rbase = (long)blockIdx.x * T_COLS;

    // ---- Coalesced load: thread t owns floats [4t, 4t+4) == float4 #t ----
    float4 v = reinterpret_cast<const float4*>(x + rbase)[t];

    // Wave-boundary prev (x[4t-1]) for lane 0 of waves > 0: L2-hit scalar load,
    // issued early so it overlaps the parameter math.
    float prevg = 0.0f;
    if (lane == 0 && t > 0) prevg = x[rbase + 4 * t - 1];

    // ---- Uniform scalar parameter work -> SGPRs ----
    float ea_p  = expf(p_alpha_log[0]);
    float eb_p  = expf(p_beta_log[0]);
    float denom = 1.0f + ea_p + eb_p;
    float omega = rfl(expf(p_omega_log[0]));
    float alpha = rfl(ea_p / denom);
    float beta  = rfl(eb_p / denom);
    float beta2 = beta * beta;
    float beta3 = beta2 * beta;
    float beta4 = beta2 * beta2;

    float x0 = v.x, x1 = v.y, x2 = v.z, x3 = v.w;

    // prev = x[4t-1]: from lane-1's x3, or the global boundary load.
    float prev = __shfl_up(x3, 1);
    if (lane == 0) prev = prevg;

    // ---- Per-thread sum/ssq (variance inputs cover the whole row) ----
    float sum = ((x0 + x1) + (x2 + x3));
    float ssq = x0 * x0;
    ssq = fmaf(x1, x1, ssq);
    ssq = fmaf(x2, x2, ssq);
    ssq = fmaf(x3, x3, ssq);

    // ---- Zero-init affine recurrence partial over this segment ----
    // t>0 : 4 steps with inputs (prev, x0, x1, x2)  -> apart = beta^4
    // t==0: 3 steps with inputs (x0, x1, x2)        -> apart = beta^3
    float z = (t > 0) ? fmaf(alpha, prev * prev, omega) : 0.0f;
    z = fmaf(beta, z, fmaf(alpha, x0 * x0, omega));
    z = fmaf(beta, z, fmaf(alpha, x1 * x1, omega));
    z = fmaf(beta, z, fmaf(alpha, x2 * x2, omega));
    float bpart = z;
    float apart = (t == 0) ? beta3 : beta4;

    // ---- Wave-level reduction (sum, ssq) ----
    float s1 = sum, s2 = ssq;
#pragma unroll
    for (int d = 32; d > 0; d >>= 1) {
        s1 += __shfl_xor(s1, d);
        s2 += __shfl_xor(s2, d);
    }

    // ---- Wave-level inclusive affine scan over (apart, bpart) ----
    float ia = apart, ib = bpart;
#pragma unroll
    for (int d = 1; d < 64; d <<= 1) {
        float pa = __shfl_up(ia, d);
        float pb = __shfl_up(ib, d);
        if (lane >= d) { ib = fmaf(ia, pb, ib); ia = ia * pa; }
    }

    // ---- Cross-wave handoff (the single barrier) ----
    if (lane == 0)  { rSum[wv] = s1; rSsq[wv] = s2; }
    if (lane == 63) { wA[wv] = ia;   wB[wv] = ib;  }
    __syncthreads();

    float tsum = 0.0f, tssq = 0.0f;
#pragma unroll
    for (int w = 0; w < NWAVES; ++w) { tsum += rSum[w]; tssq += rSsq[w]; }
    float s0 = (tssq - tsum * tsum * (1.0f / T_COLS)) * (1.0f / (T_COLS - 1));
    s0 = fmaxf(s0, 0.0f);

    // Apply preceding waves' aggregate affine maps to s0
    float sw = s0;
#pragma unroll
    for (int w = 0; w < NWAVES - 1; ++w)
        if (w < wv) sw = fmaf(wA[w], sw, wB[w]);

    // Exclusive intra-wave prefix -> entry state s = sigma2_{4t-1} (s0 for t==0)
    float pea = __shfl_up(ia, 1);
    float peb = __shfl_up(ib, 1);
    if (lane == 0) { pea = 1.0f; peb = 0.0f; }
    float s = fmaf(pea, sw, peb);

    // ---- Recompute the 4-step recurrence from the true entry state ----
    float4 q;
    if (t == 0) {
        q.x = __builtin_amdgcn_sqrtf(s);           // sigma2_0 = s0
        float zz = s;
        zz = fmaf(beta, zz, fmaf(alpha, x0 * x0, omega)); q.y = __builtin_amdgcn_sqrtf(zz);
        zz = fmaf(beta, zz, fmaf(alpha, x1 * x1, omega)); q.z = __builtin_amdgcn_sqrtf(zz);
        zz = fmaf(beta, zz, fmaf(alpha, x2 * x2, omega)); q.w = __builtin_amdgcn_sqrtf(zz);
    } else {
        float zz = s;
        zz = fmaf(beta, zz, fmaf(alpha, prev * prev, omega)); q.x = __builtin_amdgcn_sqrtf(zz);
        zz = fmaf(beta, zz, fmaf(alpha, x0 * x0, omega));     q.y = __builtin_amdgcn_sqrtf(zz);
        zz = fmaf(beta, zz, fmaf(alpha, x1 * x1, omega));     q.z = __builtin_amdgcn_sqrtf(zz);
        zz = fmaf(beta, zz, fmaf(alpha, x2 * x2, omega));     q.w = __builtin_amdgcn_sqrtf(zz);
    }

    // ---- Coalesced store: float4 #t of the row ----
    reinterpret_cast<float4*>(out + rbase)[t] = q;
}

extern "C" void kernel_launch(void* const* d_in, const int* in_sizes, int n_in,
                              void* d_out, int out_size, void* d_ws, size_t ws_size,
                              hipStream_t stream) {
    const float* x         = (const float*)d_in[0];
    const float* omega_log = (const float*)d_in[1];
    const float* alpha_log = (const float*)d_in[2];
    const float* beta_log  = (const float*)d_in[3];
    float* out = (float*)d_out;

    garch_fused<<<B_ROWS, NTHREADS, 0, stream>>>(x, omega_log, alpha_log, beta_log, out);
}

// Round 2
// 125.329 us; speedup vs baseline: 1.0138x; 1.0138x over previous
//
#include <hip/hip_runtime.h>
#include <math.h>

#define B_ROWS 4096
#define T_COLS 4096
#define NTHREADS 1024
#define NWAVES (NTHREADS / 64)   // 16
#define RPB 4                    // rows per block: 4x memory-level parallelism

// Force a (wave-uniform) float into an SGPR.
__device__ __forceinline__ float rfl(float v) {
    return __int_as_float(__builtin_amdgcn_readfirstlane(__float_as_int(v)));
}

__global__ __launch_bounds__(NTHREADS, 8) void garch_fused(
    const float* __restrict__ x,
    const float* __restrict__ p_omega_log,
    const float* __restrict__ p_alpha_log,
    const float* __restrict__ p_beta_log,
    float* __restrict__ out)
{
    // Cross-wave handoff state only: 4 arrays x RPB x NWAVES floats = 1 KB.
    __shared__ float wA[RPB][NWAVES], wB[RPB][NWAVES];
    __shared__ float rSum[RPB][NWAVES], rSsq[RPB][NWAVES];

    const int t    = threadIdx.x;
    const int lane = t & 63;
    const int wv   = t >> 6;
    const long row0 = (long)blockIdx.x * RPB;

    // ---- Issue all 4 row loads up front: 4 independent dwordx4 in flight ----
    float4 v[RPB];
#pragma unroll
    for (int r = 0; r < RPB; ++r)
        v[r] = reinterpret_cast<const float4*>(x + (row0 + r) * T_COLS)[t];

    // Wave-boundary prev (x[4t-1]) for lane 0: L2-hit scalar loads, issued early.
    float prevg[RPB];
#pragma unroll
    for (int r = 0; r < RPB; ++r) {
        prevg[r] = 0.0f;
        if (lane == 0 && t > 0) prevg[r] = x[(row0 + r) * T_COLS + 4 * t - 1];
    }

    // ---- Uniform scalar parameter work -> SGPRs ----
    float ea_p  = expf(p_alpha_log[0]);
    float eb_p  = expf(p_beta_log[0]);
    float denom = 1.0f + ea_p + eb_p;
    float omega = rfl(expf(p_omega_log[0]));
    float alpha = rfl(ea_p / denom);
    float beta  = rfl(eb_p / denom);
    float beta2 = beta * beta;
    float beta3 = beta2 * beta;
    float beta4 = beta2 * beta2;

    // ---- Per-row: prev, sum/ssq, zero-init recurrence partial ----
    float prev[RPB], s1[RPB], s2[RPB], ia[RPB], ib[RPB];
#pragma unroll
    for (int r = 0; r < RPB; ++r) {
        float x0 = v[r].x, x1 = v[r].y, x2 = v[r].z, x3 = v[r].w;

        prev[r] = __shfl_up(x3, 1);
        if (lane == 0) prev[r] = prevg[r];

        float sum = (x0 + x1) + (x2 + x3);
        float ssq = x0 * x0;
        ssq = fmaf(x1, x1, ssq);
        ssq = fmaf(x2, x2, ssq);
        ssq = fmaf(x3, x3, ssq);
        s1[r] = sum; s2[r] = ssq;

        // t>0 : 4 steps with inputs (prev, x0, x1, x2)  -> a = beta^4
        // t==0: 3 steps with inputs (x0, x1, x2)        -> a = beta^3
        float z = (t > 0) ? fmaf(alpha, prev[r] * prev[r], omega) : 0.0f;
        z = fmaf(beta, z, fmaf(alpha, x0 * x0, omega));
        z = fmaf(beta, z, fmaf(alpha, x1 * x1, omega));
        z = fmaf(beta, z, fmaf(alpha, x2 * x2, omega));
        ib[r] = z;
        ia[r] = (t == 0) ? beta3 : beta4;
    }

    // ---- Wave-level reduction (sum, ssq) — 4 rows interleaved for ILP ----
#pragma unroll
    for (int d = 32; d > 0; d >>= 1) {
#pragma unroll
        for (int r = 0; r < RPB; ++r) {
            s1[r] += __shfl_xor(s1[r], d);
            s2[r] += __shfl_xor(s2[r], d);
        }
    }

    // ---- Wave-level inclusive affine scan over (ia, ib) — interleaved ----
#pragma unroll
    for (int d = 1; d < 64; d <<= 1) {
#pragma unroll
        for (int r = 0; r < RPB; ++r) {
            float pa = __shfl_up(ia[r], d);
            float pb = __shfl_up(ib[r], d);
            if (lane >= d) { ib[r] = fmaf(ia[r], pb, ib[r]); ia[r] = ia[r] * pa; }
        }
    }

    // ---- Cross-wave handoff (the single barrier) ----
    if (lane == 0) {
#pragma unroll
        for (int r = 0; r < RPB; ++r) { rSum[r][wv] = s1[r]; rSsq[r][wv] = s2[r]; }
    }
    if (lane == 63) {
#pragma unroll
        for (int r = 0; r < RPB; ++r) { wA[r][wv] = ia[r]; wB[r][wv] = ib[r]; }
    }
    __syncthreads();

    // ---- Per-row epilogue ----
#pragma unroll
    for (int r = 0; r < RPB; ++r) {
        // Block-wide variance from the 16 wave partials (b128 broadcast reads).
        float tsum = 0.0f, tssq = 0.0f;
#pragma unroll
        for (int w4 = 0; w4 < 4; ++w4) {
            float4 a = *reinterpret_cast<const float4*>(&rSum[r][4 * w4]);
            float4 b = *reinterpret_cast<const float4*>(&rSsq[r][4 * w4]);
            tsum += (a.x + a.y) + (a.z + a.w);
            tssq += (b.x + b.y) + (b.z + b.w);
        }
        float s0 = (tssq - tsum * tsum * (1.0f / T_COLS)) * (1.0f / (T_COLS - 1));
        s0 = fmaxf(s0, 0.0f);

        // Apply preceding waves' aggregate affine maps to s0.
        float sw = s0;
#pragma unroll
        for (int w = 0; w < NWAVES - 1; ++w)
            if (w < wv) sw = fmaf(wA[r][w], sw, wB[r][w]);

        // Exclusive intra-wave prefix -> entry state s = sigma2_{4t-1}.
        float pea = __shfl_up(ia[r], 1);
        float peb = __shfl_up(ib[r], 1);
        if (lane == 0) { pea = 1.0f; peb = 0.0f; }
        float s = fmaf(pea, sw, peb);

        // Recompute the 4-step recurrence from the true entry state.
        float x0 = v[r].x, x1 = v[r].y, x2 = v[r].z;
        float4 q;
        if (t == 0) {
            q.x = __builtin_amdgcn_sqrtf(s);       // sigma2_0 = s0
            float zz = s;
            zz = fmaf(beta, zz, fmaf(alpha, x0 * x0, omega)); q.y = __builtin_amdgcn_sqrtf(zz);
            zz = fmaf(beta, zz, fmaf(alpha, x1 * x1, omega)); q.z = __builtin_amdgcn_sqrtf(zz);
            zz = fmaf(beta, zz, fmaf(alpha, x2 * x2, omega)); q.w = __builtin_amdgcn_sqrtf(zz);
        } else {
            float zz = s;
            zz = fmaf(beta, zz, fmaf(alpha, prev[r] * prev[r], omega)); q.x = __builtin_amdgcn_sqrtf(zz);
            zz = fmaf(beta, zz, fmaf(alpha, x0 * x0, omega));           q.y = __builtin_amdgcn_sqrtf(zz);
            zz = fmaf(beta, zz, fmaf(alpha, x1 * x1, omega));           q.z = __builtin_amdgcn_sqrtf(zz);
            zz = fmaf(beta, zz, fmaf(alpha, x2 * x2, omega));           q.w = __builtin_amdgcn_sqrtf(zz);
        }

        reinterpret_cast<float4*>(out + (row0 + r) * T_COLS)[t] = q;
    }
}

extern "C" void kernel_launch(void* const* d_in, const int* in_sizes, int n_in,
                              void* d_out, int out_size, void* d_ws, size_t ws_size,
                              hipStream_t stream) {
    const float* x         = (const float*)d_in[0];
    const float* omega_log = (const float*)d_in[1];
    const float* alpha_log = (const float*)d_in[2];
    const float* beta_log  = (const float*)d_in[3];
    float* out = (float*)d_out;

    garch_fused<<<B_ROWS / RPB, NTHREADS, 0, stream>>>(x, omega_log, alpha_log, beta_log, out);
}